// Round 16
// baseline (7108.121 us; speedup 1.0000x reference)
//
#include <hip/hip_runtime.h>
#include <math.h>

// Problem constants (VanillaRNN: T=129, B=1024, I=512, H=2048, k=63)
constexpr int Bsz  = 1024;
constexpr int Isz  = 512;
constexpr int Hsz  = 2048;
constexpr int Tenc = 65;   // k+2 encoder steps
constexpr int Tdec = 64;   // k+1 decoder steps
constexpr int BI   = Bsz * Isz;     // 524288
constexpr int MNh  = Bsz * Hsz;     // 2097152

typedef _Float16 half8 __attribute__((ext_vector_type(8)));
typedef float    f32x4 __attribute__((ext_vector_type(4)));
typedef unsigned int uint;
typedef unsigned short ushort;

// ---- split-f16 helpers ----------------------------------------------------
__device__ inline uint pack_split(float v) {            // element-interleaved
    _Float16 a0 = (_Float16)v;
    float r = (v - (float)a0) * 4096.f;
    _Float16 a1 = (_Float16)r;
    return ((uint)__builtin_bit_cast(ushort, a1) << 16) | __builtin_bit_cast(ushort, a0);
}
// pair -> (lo0|lo1<<16 , hi0|hi1<<16)   (plane layout)
__device__ inline void split_pair(float v0, float v1, uint& lo, uint& hi) {
    _Float16 a0 = (_Float16)v0, a1 = (_Float16)v1;
    _Float16 b0 = (_Float16)((v0 - (float)a0) * 4096.f);
    _Float16 b1 = (_Float16)((v1 - (float)a1) * 4096.f);
    lo = (uint)__builtin_bit_cast(ushort, a0) | ((uint)__builtin_bit_cast(ushort, a1) << 16);
    hi = (uint)__builtin_bit_cast(ushort, b0) | ((uint)__builtin_bit_cast(ushort, b1) << 16);
}

struct U8 { uint4 a, b; };
__device__ inline U8 ld8(const uint* __restrict__ p) {
    U8 r; r.a = *(const uint4*)p; r.b = *(const uint4*)(p + 4); return r;
}

// (fallback path helpers: element-interleaved format)
__device__ inline void split8(const U8& v, half8& lo, half8& hi) {
    union { uint4 u; float f[4]; } A, B;
    A.u = v.a; B.u = v.b;
    float x[8] = {A.f[0], A.f[1], A.f[2], A.f[3], B.f[0], B.f[1], B.f[2], B.f[3]};
#pragma unroll
    for (int e = 0; e < 8; ++e) {
        _Float16 a0 = (_Float16)x[e];
        float r = (x[e] - (float)a0) * 4096.f;
        lo[e] = a0; hi[e] = (_Float16)r;
    }
}
__device__ inline void unpack8(const U8& v, half8& lo, half8& hi) {
    union { uint u[4]; half8 h; } L, H;
    uint w[8] = {v.a.x, v.a.y, v.a.z, v.a.w, v.b.x, v.b.y, v.b.z, v.b.w};
#pragma unroll
    for (int q = 0; q < 4; ++q) {
        L.u[q] = __builtin_amdgcn_perm(w[2*q+1], w[2*q], 0x05040100u);
        H.u[q] = __builtin_amdgcn_perm(w[2*q+1], w[2*q], 0x07060302u);
    }
    lo = L.h; hi = H.h;
}

// async global(16B) -> LDS, per-lane global src, wave-uniform LDS base
__device__ __forceinline__ void gll16(const uint* g, uint* l) {
    __builtin_amdgcn_global_load_lds(
        (const __attribute__((address_space(1))) void*)(uintptr_t)g,
        (__attribute__((address_space(3))) void*)(unsigned int)(uintptr_t)l,
        16, 0, 0);
}

// L1-bypass float4 load (sc0) -- async issue; caller must s_waitcnt vmcnt(0)
// + sched_barrier(0) before USING the result (rule #18).
__device__ __forceinline__ float4 ldc4(const float* p) {
    float4 v;
    asm volatile("global_load_dwordx4 %0, %1, off sc0" : "=&v"(v) : "v"(p));
    return v;
}

// ===========================================================================
// Split-K split-f16 GEMM body — PLANE-INTERLEAVED layout (verified r15).
// REDUCE: last-of-4 split-K blocks per tile (same-XCD by n-strip decode)
// sums the 4 f32 partials, applies bias+tanh, packs h directly (no combine
// kernel). Protocol validated r10: vmcnt(0) drain + relaxed agent atomic +
// sc0 L1-bypass reads within one XCD's L2.
// ===========================================================================
template<bool REDUCE>
__device__ __forceinline__ void gemm_body(
    uint* ldsA, uint* ldsB,
    const uint* A1, int K1, const uint* B1,
    const uint* A2, int K2, const uint* B2,
    float* P, int M, int N, int GM, int GN, int KS, int bid,
    const float* bias1, const float* bias2, uint* hout, uint* cnt)
{
    constexpr int NV = 8;            // gll16 per STAGE per thread (4 A + 4 B)
    const int tid  = threadIdx.x;
    const int wid  = tid >> 6, lane = tid & 63;
    const int wr   = wid >> 1, wc = wid & 1;
    const int kq   = lane >> 4, lr = lane & 15;

    // ---- XCD-stable block decode: n-strip pinned to an XCD ----
    const int xcd = bid & 7, g = bid >> 3;
    int n_b, m_b, ks;
    const int spx = GN >> 3;
    if (spx > 0) {
        n_b = xcd * spx + (g % spx);
        int r = g / spx; m_b = r % GM; ks = r / GM;
    } else {
        const int xpn = 8 / GN;
        n_b = xcd / xpn;
        int r = g * xpn + (xcd % xpn); m_b = r % GM; ks = r / GM;
    }
    const int m0 = m_b * 128, n0 = n_b * 128;

    int offA1[4], offA2[4], offB1[4], offB2[4];
#pragma unroll
    for (int q = 0; q < 4; ++q) {
        int U = q * 256 + tid, row = U >> 3, us = U & 7;
        int u = us ^ (row & 7);                   // inverse read-swizzle
        offA1[q] = (m0 + row) * K1 + u * 4;
        offA2[q] = (m0 + row) * K2 + u * 4;
        offB1[q] = (n0 + row) * K1 + u * 4;
        offB2[q] = (n0 + row) * K2 + u * 4;
    }
    const int ldsbase = wid * 256;

    const int R1 = K1 / 32;
    const int R  = (K1 + K2) / 32;
    const int nr = R / KS;
    const int r0 = ks * nr;

    auto STAGE = [&](int r, int bi) {
        uint* Ab = ldsA + bi * 4096;
        uint* Bb = ldsB + bi * 4096;
        const bool ph1 = r < R1;
        const int kl = (ph1 ? r : r - R1) * 32;
        const uint* As = ph1 ? A1 : A2;
        const uint* Bs = ph1 ? B1 : B2;
#pragma unroll
        for (int q = 0; q < 4; ++q)
            gll16(As + (ph1 ? offA1[q] : offA2[q]) + kl, Ab + q * 1024 + ldsbase);
#pragma unroll
        for (int q = 0; q < 4; ++q)
            gll16(Bs + (ph1 ? offB1[q] : offB2[q]) + kl, Bb + q * 1024 + ldsbase);
    };

    f32x4 acc0[4][4] = {}; f32x4 acc1[4][4] = {};

    // direct half8 fragment loads: lo = unit kq, hi = unit kq+4 (swizzled)
    auto FRAG = [&](const uint* buf, int row, half8& lo, half8& hi) {
        const int b = row * 8, s = row & 7;
        lo = *(const half8*)(buf + (b + (kq ^ s)) * 4);
        hi = *(const half8*)(buf + (b + ((kq + 4) ^ s)) * 4);
    };

    auto COMPUTE = [&](int bi) {
        const uint* Ab = ldsA + bi * 4096;
        const uint* Bb = ldsB + bi * 4096;
        half8 a0[4], a1[4];
#pragma unroll
        for (int i = 0; i < 4; ++i) FRAG(Ab, wr * 64 + i * 16 + lr, a0[i], a1[i]);
#pragma unroll
        for (int j = 0; j < 4; ++j) {
            half8 b0, b1;
            FRAG(Bb, wc * 64 + j * 16 + lr, b0, b1);
#pragma unroll
            for (int i = 0; i < 4; ++i) {
                acc0[i][j] = __builtin_amdgcn_mfma_f32_16x16x32_f16(a0[i], b0, acc0[i][j], 0, 0, 0);
                acc1[i][j] = __builtin_amdgcn_mfma_f32_16x16x32_f16(a1[i], b0, acc1[i][j], 0, 0, 0);
                acc1[i][j] = __builtin_amdgcn_mfma_f32_16x16x32_f16(a0[i], b1, acc1[i][j], 0, 0, 0);
            }
        }
    };

    STAGE(r0, 0);
    if (nr > 1) STAGE(r0 + 1, 1);
    __builtin_amdgcn_sched_barrier(0);
    if (nr > 1) asm volatile("s_waitcnt vmcnt(%0)" :: "i"(NV) : "memory");
    else        asm volatile("s_waitcnt vmcnt(0)"  ::: "memory");
    __builtin_amdgcn_s_barrier();
    __builtin_amdgcn_sched_barrier(0);

    int bi = 0;
    for (int t = 0; t < nr; ++t) {
        COMPUTE(bi);
        if (t + 1 < nr) {
            __builtin_amdgcn_sched_barrier(0);
            __builtin_amdgcn_s_barrier();          // all waves done reading bi
            __builtin_amdgcn_sched_barrier(0);
            if (t + 2 < nr) {
                STAGE(r0 + t + 2, bi);
                __builtin_amdgcn_sched_barrier(0);
                asm volatile("s_waitcnt vmcnt(%0)" :: "i"(NV) : "memory");
            } else {
                asm volatile("s_waitcnt vmcnt(0)" ::: "memory");
            }
            __builtin_amdgcn_s_barrier();          // t+1 data visible
            __builtin_amdgcn_sched_barrier(0);
            bi ^= 1;
        }
    }

    float* Pk = P + (size_t)ks * M * N;
#pragma unroll
    for (int j = 0; j < 4; ++j) {
        const int n = n0 + wc * 64 + j * 16 + lr;
#pragma unroll
        for (int i = 0; i < 4; ++i) {
            const int mb = m0 + wr * 64 + i * 16 + kq * 4;
#pragma unroll
            for (int r = 0; r < 4; ++r)
                Pk[(size_t)(mb + r) * N + n] = acc0[i][j][r] + 0x1p-12f * acc1[i][j][r];
        }
    }

    if (REDUCE) {
        // drain this wave's partial stores to L2, then all-wave rendezvous
        asm volatile("s_waitcnt vmcnt(0)" ::: "memory");
        __syncthreads();
        __shared__ uint sold;
        if (tid == 0)
            sold = __hip_atomic_fetch_add(cnt + (m_b * GN + n_b), 1u,
                       __ATOMIC_RELAXED, __HIP_MEMORY_SCOPE_AGENT);
        __syncthreads();
        if ((sold & 3) == 3) {     // last of the 4 split-K blocks (same XCD)
            for (int e = tid; e < 2048; e += 256) {
                const int row = e >> 4;
                const int col = (e & 15) << 3;
                const int gm = m0 + row, gn = n0 + col;
                const size_t idx = (size_t)gm * N + gn;
                float4 va[4], vb[4];
#pragma unroll
                for (int p = 0; p < 4; ++p) {
                    va[p] = ldc4(P + (size_t)p * M * N + idx);
                    vb[p] = ldc4(P + (size_t)p * M * N + idx + 4);
                }
                asm volatile("s_waitcnt vmcnt(0)" ::: "memory");
                __builtin_amdgcn_sched_barrier(0);
                float t8[8];
                t8[0] = va[0].x + va[1].x + va[2].x + va[3].x;
                t8[1] = va[0].y + va[1].y + va[2].y + va[3].y;
                t8[2] = va[0].z + va[1].z + va[2].z + va[3].z;
                t8[3] = va[0].w + va[1].w + va[2].w + va[3].w;
                t8[4] = vb[0].x + vb[1].x + vb[2].x + vb[3].x;
                t8[5] = vb[0].y + vb[1].y + vb[2].y + vb[3].y;
                t8[6] = vb[0].z + vb[1].z + vb[2].z + vb[3].z;
                t8[7] = vb[0].w + vb[1].w + vb[2].w + vb[3].w;
#pragma unroll
                for (int q = 0; q < 8; ++q)
                    t8[q] = tanhf(t8[q] + bias1[gn + q] + bias2[gn + q]);
                uint lo4[4], hi4[4];
#pragma unroll
                for (int q = 0; q < 4; ++q)
                    split_pair(t8[2*q], t8[2*q+1], lo4[q], hi4[q]);
                uint* base = hout + (size_t)gm * N + (gn & ~31);
                const int eo = (gn & 31) >> 1;
                *(uint4*)(base + eo)      = *(uint4*)lo4;
                *(uint4*)(base + 16 + eo) = *(uint4*)hi4;
            }
        }
    }
}

// ---------------------------------------------------------------------------
// h-GEMM with fused split-K reduction epilogue (encoder & decoder prologue)
// ---------------------------------------------------------------------------
__global__ __launch_bounds__(256, 2) void gemm_red(
    const uint* __restrict__ A1, int K1, const uint* __restrict__ B1,
    const uint* __restrict__ A2, int K2, const uint* __restrict__ B2,
    float* __restrict__ P, int M, int N, int GM, int GN, int KS,
    const float* __restrict__ b1, const float* __restrict__ b2,
    uint* __restrict__ hout, uint* __restrict__ cnt)
{
    __shared__ uint ldsA[2 * 4096];
    __shared__ uint ldsB[2 * 4096];
    gemm_body<true>(ldsA, ldsB, A1, K1, B1, A2, K2, B2,
                    P, M, N, GM, GN, KS, blockIdx.x, b1, b2, hout, cnt);
}

// ---------------------------------------------------------------------------
// Fused decoder work (grid 640):
//   bid <  512 -> h-GEMM(h_t -> h_{t+1} via fused reduce)  [if doH]
//   512-639    -> ro-GEMM(h_t -> ropar, KS=4, nr=16)
// Both only READ h_t (pipelined dataflow verified r9/r12).
// ---------------------------------------------------------------------------
__global__ __launch_bounds__(256, 2) void dec_work(
    const uint* __restrict__ hcur, const uint* __restrict__ pdWhh,
    const uint* __restrict__ proW,
    float* __restrict__ hparts, float* __restrict__ ropar,
    const float* __restrict__ dbih, const float* __restrict__ dbhh,
    uint* __restrict__ hout, uint* __restrict__ cnt, int doH)
{
    __shared__ uint ldsA[2 * 4096];
    __shared__ uint ldsB[2 * 4096];
    const int bid = blockIdx.x;
    if (bid < 512) {
        if (!doH) return;
        gemm_body<true>(ldsA, ldsB, nullptr, 0, nullptr, hcur, Hsz, pdWhh,
                        hparts, Bsz, Hsz, 8, 16, 4, bid, dbih, dbhh, hout, cnt);
    } else {
        gemm_body<false>(ldsA, ldsB, nullptr, 0, nullptr, hcur, Hsz, proW,
                         ropar, Bsz, Isz, 8, 4, 4, bid - 512,
                         nullptr, nullptr, nullptr, nullptr);
    }
}

// ---------------------------------------------------------------------------
// log_softmax over Isz=512 (rob + NPART partials), argmax==2, done-latch
// ---------------------------------------------------------------------------
template<int NPART>
__device__ __forceinline__ void softmax_dev(
    const float* __restrict__ parts, const float* __restrict__ rob,
    float* __restrict__ done, float* __restrict__ out, int b)
{
    const int tid = threadIdx.x;
    const size_t S = (size_t)BI;
    const float* row = parts + (size_t)b * Isz;

    float v0, v1;
    if (NPART == 1) { v0 = row[tid]; v1 = row[tid + 256]; }
    else {
        v0 = rob[tid]; v1 = rob[tid + 256];
#pragma unroll
        for (int p = 0; p < NPART; ++p) { v0 += row[p*S + tid]; v1 += row[p*S + tid + 256]; }
    }

    float mv; int mi;
    if (v0 >= v1) { mv = v0; mi = tid; } else { mv = v1; mi = tid + 256; }
#pragma unroll
    for (int off = 32; off; off >>= 1) {
        float ov = __shfl_xor(mv, off);
        int   oi = __shfl_xor(mi, off);
        if (ov > mv || (ov == mv && oi < mi)) { mv = ov; mi = oi; }
    }
    __shared__ float smv[4];
    __shared__ int   smi[4];
    __shared__ float sdone;
    const int wid = tid >> 6, lane = tid & 63;
    if (lane == 0) { smv[wid] = mv; smi[wid] = mi; }
    __syncthreads();
    if (tid == 0) {
        for (int w = 1; w < 4; ++w)
            if (smv[w] > smv[0] || (smv[w] == smv[0] && smi[w] < smi[0])) {
                smv[0] = smv[w]; smi[0] = smi[w];
            }
        float z = (smi[0] == 2) ? 1.f : 0.f;
        float dn = fmaxf(done[b], z);
        done[b] = dn;
        sdone = dn;
    }
    __syncthreads();
    mv = smv[0];

    float s = expf(v0 - mv) + expf(v1 - mv);
#pragma unroll
    for (int off = 32; off; off >>= 1) s += __shfl_xor(s, off);
    __shared__ float ssum[4];
    if (lane == 0) ssum[wid] = s;
    __syncthreads();
    if (tid == 0) ssum[0] = ssum[0] + ssum[1] + ssum[2] + ssum[3];
    __syncthreads();
    const float ls = logf(ssum[0]);

    float* orow = out + (size_t)b * Isz;
    if (sdone > 0.5f) {
        orow[tid]       = (tid == 0) ? 1.f : 0.f;
        orow[tid + 256] = 0.f;
    } else {
        orow[tid]       = v0 - mv - ls;
        orow[tid + 256] = v1 - mv - ls;
    }
}

// Decoder finish: softmax only (grid 1024, one row per block)
__global__ __launch_bounds__(256) void dec_fin(
    const float* __restrict__ ropar, const float* __restrict__ rob,
    float* __restrict__ done, float* __restrict__ out)
{
    softmax_dev<4>(ropar, rob, done, out, blockIdx.x);
}

// Fallback softmax (single partial)
__global__ __launch_bounds__(256) void logsoftmax_done1(
    const float* __restrict__ logits, const float* __restrict__ rob,
    float* __restrict__ done, float* __restrict__ out)
{
    softmax_dev<1>(logits, rob, done, out, blockIdx.x);
}

// ---------------------------------------------------------------------------
// f32 -> PLANE-layout packed split (verified r15)
// ---------------------------------------------------------------------------
__global__ __launch_bounds__(256) void split_pack2_k(
    const float* __restrict__ s, uint* __restrict__ d, int n)
{
    for (int i = blockIdx.x * 256 + threadIdx.x; i < n; i += gridDim.x * 256) {
        const int c = i >> 5, j = i & 31;
        const int kb = c << 5;
        uint v;
        if (j < 16) {
            const int k = kb + (j << 1);
            _Float16 a0 = (_Float16)s[k], a1 = (_Float16)s[k + 1];
            v = (uint)__builtin_bit_cast(ushort, a0) |
                ((uint)__builtin_bit_cast(ushort, a1) << 16);
        } else {
            const int k = kb + ((j - 16) << 1);
            float f0 = s[k], f1 = s[k + 1];
            _Float16 b0 = (_Float16)((f0 - (float)(_Float16)f0) * 4096.f);
            _Float16 b1 = (_Float16)((f1 - (float)(_Float16)f1) * 4096.f);
            v = (uint)__builtin_bit_cast(ushort, b0) |
                ((uint)__builtin_bit_cast(ushort, b1) << 16);
        }
        d[i] = v;
    }
}

// ===========================================================================
// FALLBACK PATH (tiny ws): reg-staged split-f16 GEMM, fp32 B (unchanged)
// ===========================================================================
#define SWZ(row, kk) (((row) * 4 + ((kk) ^ (((row) >> 1) & 3))) * 8)

template<int BM, int BN, int WR, int WC, int MP, int NP, bool TANH, bool PACKOUT>
__global__ __launch_bounds__(WR*WC*64) void gemm_sp(
    const float* __restrict__ A1, int K1, const void* __restrict__ B1,
    const uint*  __restrict__ A2, int K2, const void* __restrict__ B2,
    int b_f32,
    const float* __restrict__ bias1, const float* __restrict__ bias2,
    void* __restrict__ C, int M, int N)
{
    constexpr int NT  = WR * WC * 64;
    constexpr int AUP = BM * 4 / NT;
    constexpr int BUP = BN * 4 / NT;

    __shared__ __align__(16) _Float16 As0[BM*32], As1[BM*32];
    __shared__ __align__(16) _Float16 Bs0[BN*32], Bs1[BN*32];

    const int tid  = threadIdx.x;
    const int wid  = tid >> 6, lane = tid & 63;
    const int wrow = wid / WC, wcol = wid % WC;
    const int kq   = lane >> 4, lr = lane & 15;
    const int m0   = blockIdx.y * BM;
    const int n0   = blockIdx.x * BN;

    int aum[AUP], auk[AUP]; _Float16 *aw0[AUP], *aw1[AUP];
#pragma unroll
    for (int p = 0; p < AUP; ++p) {
        int u = tid + p * NT; aum[p] = u >> 2; auk[p] = u & 3;
        int o = SWZ(aum[p], auk[p]); aw0[p] = As0 + o; aw1[p] = As1 + o;
    }
    int bun[BUP], buk[BUP]; _Float16 *bw0[BUP], *bw1[BUP];
#pragma unroll
    for (int p = 0; p < BUP; ++p) {
        int u = tid + p * NT; bun[p] = u >> 2; buk[p] = u & 3;
        int o = SWZ(bun[p], buk[p]); bw0[p] = Bs0 + o; bw1[p] = Bs1 + o;
    }
    int aoff[MP], boff[NP];
#pragma unroll
    for (int i = 0; i < MP; ++i) { int m = wrow*(MP*16) + i*16 + lr; aoff[i] = SWZ(m, kq); }
#pragma unroll
    for (int j = 0; j < NP; ++j) { int n = wcol*(NP*16) + j*16 + lr; boff[j] = SWZ(n, kq); }

    f32x4 acc0[MP][NP] = {}; f32x4 acc1[MP][NP] = {};

    const int R = (K1 + K2) / 32;

    auto issue = [&](int rd, U8* aR, U8* bR) {
        const bool ph1 = (rd * 32) < K1;
        const int  kl  = ph1 ? rd * 32 : rd * 32 - K1;
        const int  Ka  = ph1 ? K1 : K2;
        const uint* Ap = ph1 ? (const uint*)A1 : A2;
        const uint* Bp = (const uint*)(ph1 ? B1 : B2);
#pragma unroll
        for (int p = 0; p < AUP; ++p)
            aR[p] = ld8(Ap + (size_t)(m0 + aum[p]) * Ka + kl + auk[p] * 8);
#pragma unroll
        for (int p = 0; p < BUP; ++p)
            bR[p] = ld8(Bp + (size_t)(n0 + bun[p]) * Ka + kl + buk[p] * 8);
    };

    auto stage = [&](U8* aR, U8* bR, bool aF32) {
#pragma unroll
        for (int p = 0; p < AUP; ++p) {
            half8 lo, hi;
            if (aF32) split8(aR[p], lo, hi); else unpack8(aR[p], lo, hi);
            *(half8*)aw0[p] = lo; *(half8*)aw1[p] = hi;
        }
#pragma unroll
        for (int p = 0; p < BUP; ++p) {
            half8 lo, hi;
            if (b_f32) split8(bR[p], lo, hi); else unpack8(bR[p], lo, hi);
            *(half8*)bw0[p] = lo; *(half8*)bw1[p] = hi;
        }
    };

    auto compute = [&]() {
        half8 a0[MP], a1[MP], b0[NP], b1[NP];
#pragma unroll
        for (int i = 0; i < MP; ++i) {
            a0[i] = *(const half8*)(As0 + aoff[i]);
            a1[i] = *(const half8*)(As1 + aoff[i]);
        }
#pragma unroll
        for (int j = 0; j < NP; ++j) {
            b0[j] = *(const half8*)(Bs0 + boff[j]);
            b1[j] = *(const half8*)(Bs1 + boff[j]);
        }
#pragma unroll
        for (int i = 0; i < MP; ++i)
#pragma unroll
            for (int j = 0; j < NP; ++j) {
                acc0[i][j] = __builtin_amdgcn_mfma_f32_16x16x32_f16(a0[i], b0[j], acc0[i][j], 0, 0, 0);
                acc1[i][j] = __builtin_amdgcn_mfma_f32_16x16x32_f16(a1[i], b0[j], acc1[i][j], 0, 0, 0);
                acc1[i][j] = __builtin_amdgcn_mfma_f32_16x16x32_f16(a0[i], b1[j], acc1[i][j], 0, 0, 0);
            }
    };

    U8 aA[AUP], bA[BUP], aB[AUP], bB[BUP];
    issue(0, aA, bA);
    for (int rd = 0; rd < R; rd += 2) {
        if (rd + 1 < R) issue(rd + 1, aB, bB);
        stage(aA, bA, (rd * 32) < K1);
        __syncthreads();
        compute();
        __syncthreads();
        if (rd + 1 < R) {
            if (rd + 2 < R) issue(rd + 2, aA, bA);
            stage(aB, bB, ((rd + 1) * 32) < K1);
            __syncthreads();
            compute();
            __syncthreads();
        }
    }

#pragma unroll
    for (int j = 0; j < NP; ++j) {
        const int n = n0 + wcol*(NP*16) + j*16 + lr;
        float bb = bias1 ? bias1[n] : 0.f;
        if (bias2) bb += bias2[n];
#pragma unroll
        for (int i = 0; i < MP; ++i) {
            const int mb = m0 + wrow*(MP*16) + i*16 + kq*4;
#pragma unroll
            for (int r = 0; r < 4; ++r) {
                float val = acc0[i][j][r] + 0x1p-12f * acc1[i][j][r] + bb;
                if (TANH) val = tanhf(val);
                if (PACKOUT)
                    ((uint*)C)[(size_t)(mb + r) * N + n] = pack_split(val);
                else
                    ((float*)C)[(size_t)(mb + r) * N + n] = val;
            }
        }
    }
}

// ---------------------------------------------------------------------------
extern "C" void kernel_launch(void* const* d_in, const int* in_sizes, int n_in,
                              void* d_out, int out_size, void* d_ws, size_t ws_size,
                              hipStream_t stream)
{
    const float* x    = (const float*)d_in[0];
    const float* eWih = (const float*)d_in[1];
    const float* eWhh = (const float*)d_in[2];
    const float* ebih = (const float*)d_in[3];
    const float* ebhh = (const float*)d_in[4];
    const float* dWhh = (const float*)d_in[6];
    const float* dbih = (const float*)d_in[7];
    const float* dbhh = (const float*)d_in[8];
    const float* roW  = (const float*)d_in[9];
    const float* rob  = (const float*)d_in[10];
    float* out = (float*)d_out;

    const size_t sz_pWih = (size_t)Hsz * Isz * 4;        //  4 MB
    const size_t sz_pWhh = (size_t)Hsz * Hsz * 4;        // 16 MB
    const size_t sz_proW = (size_t)Isz * Hsz * 4;        //  4 MB
    const size_t sz_h    = (size_t)MNh * 4;              //  8 MB packed
    const size_t sz_hp   = (size_t)4 * MNh * 4;          // 32 MB h partials
    const size_t sz_rp   = (size_t)4 * BI * 4;           //  8 MB ro partials
    const size_t sz_done = (size_t)Bsz * 4;
    const size_t sz_cnt  = 512;
    const size_t sz_px2  = (size_t)Tenc * BI * 4;        // 136 MB
    const size_t sz_slot = (size_t)BI * 4;               //   2 MB

    const size_t base = sz_pWih + 2*sz_pWhh + sz_proW + 2*sz_h + sz_hp + sz_rp
                      + sz_done + sz_cnt;
    const int mode = (ws_size >= base + sz_px2) ? 2
                   : (ws_size >= base + sz_slot) ? 1 : 0;

    char* ws = (char*)d_ws;

    if (mode >= 1) {
        size_t off = 0;
        uint* pWih   = (uint*)(ws + off); off += sz_pWih;
        uint* pWhh   = (uint*)(ws + off); off += sz_pWhh;
        uint* pdWhh  = (uint*)(ws + off); off += sz_pWhh;
        uint* proW   = (uint*)(ws + off); off += sz_proW;
        uint* hA     = (uint*)(ws + off); off += sz_h;
        uint* hB     = (uint*)(ws + off); off += sz_h;
        float* hparts= (float*)(ws + off); off += sz_hp;
        float* ropar = (float*)(ws + off); off += sz_rp;
        float* done  = (float*)(ws + off); off += sz_done;
        uint* cnt    = (uint*)(ws + off);  off += sz_cnt;
        uint* px     = (uint*)(ws + off);   // mode2: 65 steps; mode1: 1 slot

        split_pack2_k<<<dim3(1024), dim3(256), 0, stream>>>(eWih, pWih,  Hsz*Isz);
        split_pack2_k<<<dim3(2048), dim3(256), 0, stream>>>(eWhh, pWhh,  Hsz*Hsz);
        split_pack2_k<<<dim3(2048), dim3(256), 0, stream>>>(dWhh, pdWhh, Hsz*Hsz);
        split_pack2_k<<<dim3(1024), dim3(256), 0, stream>>>(roW,  proW,  Isz*Hsz);
        if (mode == 2)
            split_pack2_k<<<dim3(2048), dim3(256), 0, stream>>>(x, px, Tenc*BI);

        hipMemsetAsync(hA,   0, sz_h,    stream);
        hipMemsetAsync(done, 0, sz_done, stream);
        hipMemsetAsync(cnt,  0, sz_cnt,  stream);

        uint* h[2] = { hA, hB };
        int cur = 0;
        // ---- encoder: ONE launch/step (GEMM + fused split-K reduce) ----
        for (int t = 0; t < Tenc; ++t) {
            const uint* xs;
            if (mode == 2) xs = px + (size_t)t * BI;
            else {
                split_pack2_k<<<dim3(512), dim3(256), 0, stream>>>(
                    x + (size_t)t * BI, px, BI);
                xs = px;
            }
            gemm_red<<<dim3(512), dim3(256), 0, stream>>>(
                xs, Isz, pWih, h[cur], Hsz, pWhh,
                hparts, Bsz, Hsz, 8, 16, 4,
                ebih, ebhh, h[cur ^ 1], cnt);
            cur ^= 1;
        }
        // ---- decoder prologue: h_1 = tanh(bias + h_enc @ Whh^T) ----
        gemm_red<<<dim3(512), dim3(256), 0, stream>>>(
            nullptr, 0, nullptr, h[cur], Hsz, pdWhh,
            hparts, Bsz, Hsz, 8, 16, 4,
            dbih, dbhh, h[cur ^ 1], cnt);
        cur ^= 1;
        // ---- decoder: 64 steps x 2 launches ----
        // dec_work: ro(h_t)->ropar || h-GEMM+reduce(h_t)->h_{t+1} (skip last)
        // dec_fin : softmax(ropar)->out[t]
        for (int t = 0; t < Tdec; ++t) {
            const int doH = (t + 1 < Tdec) ? 1 : 0;
            dec_work<<<dim3(640), dim3(256), 0, stream>>>(
                h[cur], pdWhh, proW, hparts, ropar,
                dbih, dbhh, h[cur ^ 1], cnt, doH);
            dec_fin<<<dim3(1024), dim3(256), 0, stream>>>(
                ropar, rob, done, out + (size_t)t * BI);
            cur ^= 1;
        }
        return;
    }

    // ================= fallback path (tiny ws) =================
    {
        const size_t sz_lg = (size_t)BI * 4;
        size_t off = 0;
        uint*  hA     = (uint*)(ws + off); off += sz_h;
        uint*  hB     = (uint*)(ws + off); off += sz_h;
        float* logits = (float*)(ws + off); off += sz_lg;
        float* done   = (float*)(ws + off);

        hipMemsetAsync(hA, 0, sz_h, stream);
        hipMemsetAsync(done, 0, sz_done, stream);

        uint* h[2] = { hA, hB };
        const dim3 blk(256);
        const dim3 grid_h(Hsz / 128, Bsz / 64);
        const dim3 grid_ro(Isz / 64, Bsz / 64);

        int cur = 0;
        for (int t = 0; t < Tenc; ++t) {
            gemm_sp<64, 128, 2, 2, 2, 4, true, true><<<grid_h, blk, 0, stream>>>(
                x + (size_t)t * BI, Isz, eWih,
                h[cur], Hsz, eWhh, 1,
                ebih, ebhh, h[cur ^ 1], Bsz, Hsz);
            cur ^= 1;
        }
        for (int t = 0; t < Tdec; ++t) {
            gemm_sp<64, 128, 2, 2, 2, 4, true, true><<<grid_h, blk, 0, stream>>>(
                nullptr, 0, nullptr, h[cur], Hsz, dWhh, 1,
                dbih, dbhh, h[cur ^ 1], Bsz, Hsz);
            cur ^= 1;
            gemm_sp<64, 64, 2, 2, 2, 2, false, false><<<grid_ro, blk, 0, stream>>>(
                nullptr, 0, nullptr, h[cur], Hsz, roW, 1,
                rob, nullptr, logits, Bsz, Isz);
            logsoftmax_done1<<<dim3(Bsz), dim3(256), 0, stream>>>(
                logits, rob, done, out + (size_t)t * BI);
        }
    }
}

// Round 17
// 6187.551 us; speedup vs baseline: 1.1488x; 1.1488x over previous
//
#include <hip/hip_runtime.h>
#include <math.h>

// Problem constants (VanillaRNN: T=129, B=1024, I=512, H=2048, k=63)
constexpr int Bsz  = 1024;
constexpr int Isz  = 512;
constexpr int Hsz  = 2048;
constexpr int Tenc = 65;   // k+2 encoder steps
constexpr int Tdec = 64;   // k+1 decoder steps
constexpr int BI   = Bsz * Isz;     // 524288
constexpr int MNh  = Bsz * Hsz;     // 2097152

typedef _Float16 half8 __attribute__((ext_vector_type(8)));
typedef float    f32x4 __attribute__((ext_vector_type(4)));
typedef unsigned int uint;
typedef unsigned short ushort;

// ---- split-f16 helpers ----------------------------------------------------
__device__ inline uint pack_split(float v) {            // element-interleaved
    _Float16 a0 = (_Float16)v;
    float r = (v - (float)a0) * 4096.f;
    _Float16 a1 = (_Float16)r;
    return ((uint)__builtin_bit_cast(ushort, a1) << 16) | __builtin_bit_cast(ushort, a0);
}
// pair -> (lo0|lo1<<16 , hi0|hi1<<16)   (plane layout)
__device__ inline void split_pair(float v0, float v1, uint& lo, uint& hi) {
    _Float16 a0 = (_Float16)v0, a1 = (_Float16)v1;
    _Float16 b0 = (_Float16)((v0 - (float)a0) * 4096.f);
    _Float16 b1 = (_Float16)((v1 - (float)a1) * 4096.f);
    lo = (uint)__builtin_bit_cast(ushort, a0) | ((uint)__builtin_bit_cast(ushort, a1) << 16);
    hi = (uint)__builtin_bit_cast(ushort, b0) | ((uint)__builtin_bit_cast(ushort, b1) << 16);
}

struct U8 { uint4 a, b; };
__device__ inline U8 ld8(const uint* __restrict__ p) {
    U8 r; r.a = *(const uint4*)p; r.b = *(const uint4*)(p + 4); return r;
}

// (fallback path helpers: element-interleaved format)
__device__ inline void split8(const U8& v, half8& lo, half8& hi) {
    union { uint4 u; float f[4]; } A, B;
    A.u = v.a; B.u = v.b;
    float x[8] = {A.f[0], A.f[1], A.f[2], A.f[3], B.f[0], B.f[1], B.f[2], B.f[3]};
#pragma unroll
    for (int e = 0; e < 8; ++e) {
        _Float16 a0 = (_Float16)x[e];
        float r = (x[e] - (float)a0) * 4096.f;
        lo[e] = a0; hi[e] = (_Float16)r;
    }
}
__device__ inline void unpack8(const U8& v, half8& lo, half8& hi) {
    union { uint u[4]; half8 h; } L, H;
    uint w[8] = {v.a.x, v.a.y, v.a.z, v.a.w, v.b.x, v.b.y, v.b.z, v.b.w};
#pragma unroll
    for (int q = 0; q < 4; ++q) {
        L.u[q] = __builtin_amdgcn_perm(w[2*q+1], w[2*q], 0x05040100u);
        H.u[q] = __builtin_amdgcn_perm(w[2*q+1], w[2*q], 0x07060302u);
    }
    lo = L.h; hi = H.h;
}

// async global(16B) -> LDS, per-lane global src, wave-uniform LDS base
__device__ __forceinline__ void gll16(const uint* g, uint* l) {
    __builtin_amdgcn_global_load_lds(
        (const __attribute__((address_space(1))) void*)(uintptr_t)g,
        (__attribute__((address_space(3))) void*)(unsigned int)(uintptr_t)l,
        16, 0, 0);
}

// ===========================================================================
// Split-K split-f16 GEMM body — PLANE-INTERLEAVED layout (verified r15)
// + T5 s_setprio around the MFMA cluster (2 blocks/CU => role diversity).
// Tile 128x128, BK=32, 4 waves (2x2), wave-tile 64x64, 2-buffer LDS
// ping-pong (64 KiB -> 2 blocks/CU), global_load_lds staging, counted vmcnt.
// LDS: unit u of a row stored at position u^(row&7); inverse swizzle is
// pre-applied to the GLOBAL source address (LDS dest stays linear).
// XCD-stable decode: n-strip pinned to an XCD (weight slice L2-resident).
// ===========================================================================
__device__ __forceinline__ void gemm_body(
    uint* ldsA, uint* ldsB,
    const uint* A1, int K1, const uint* B1,
    const uint* A2, int K2, const uint* B2,
    float* P, int M, int N, int GM, int GN, int KS, int bid)
{
    constexpr int NV = 8;            // gll16 per STAGE per thread (4 A + 4 B)
    const int tid  = threadIdx.x;
    const int wid  = tid >> 6, lane = tid & 63;
    const int wr   = wid >> 1, wc = wid & 1;
    const int kq   = lane >> 4, lr = lane & 15;

    // ---- XCD-stable block decode: n-strip pinned to an XCD ----
    const int xcd = bid & 7, g = bid >> 3;
    int n_b, m_b, ks;
    const int spx = GN >> 3;
    if (spx > 0) {
        n_b = xcd * spx + (g % spx);
        int r = g / spx; m_b = r % GM; ks = r / GM;
    } else {
        const int xpn = 8 / GN;
        n_b = xcd / xpn;
        int r = g * xpn + (xcd % xpn); m_b = r % GM; ks = r / GM;
    }
    const int m0 = m_b * 128, n0 = n_b * 128;

    int offA1[4], offA2[4], offB1[4], offB2[4];
#pragma unroll
    for (int q = 0; q < 4; ++q) {
        int U = q * 256 + tid, row = U >> 3, us = U & 7;
        int u = us ^ (row & 7);                   // inverse read-swizzle
        offA1[q] = (m0 + row) * K1 + u * 4;
        offA2[q] = (m0 + row) * K2 + u * 4;
        offB1[q] = (n0 + row) * K1 + u * 4;
        offB2[q] = (n0 + row) * K2 + u * 4;
    }
    const int ldsbase = wid * 256;

    const int R1 = K1 / 32;
    const int R  = (K1 + K2) / 32;
    const int nr = R / KS;
    const int r0 = ks * nr;

    auto STAGE = [&](int r, int bi) {
        uint* Ab = ldsA + bi * 4096;
        uint* Bb = ldsB + bi * 4096;
        const bool ph1 = r < R1;
        const int kl = (ph1 ? r : r - R1) * 32;
        const uint* As = ph1 ? A1 : A2;
        const uint* Bs = ph1 ? B1 : B2;
#pragma unroll
        for (int q = 0; q < 4; ++q)
            gll16(As + (ph1 ? offA1[q] : offA2[q]) + kl, Ab + q * 1024 + ldsbase);
#pragma unroll
        for (int q = 0; q < 4; ++q)
            gll16(Bs + (ph1 ? offB1[q] : offB2[q]) + kl, Bb + q * 1024 + ldsbase);
    };

    f32x4 acc0[4][4] = {}; f32x4 acc1[4][4] = {};

    // direct half8 fragment loads: lo = unit kq, hi = unit kq+4 (swizzled)
    auto FRAG = [&](const uint* buf, int row, half8& lo, half8& hi) {
        const int b = row * 8, s = row & 7;
        lo = *(const half8*)(buf + (b + (kq ^ s)) * 4);
        hi = *(const half8*)(buf + (b + ((kq + 4) ^ s)) * 4);
    };

    auto COMPUTE = [&](int bi) {
        const uint* Ab = ldsA + bi * 4096;
        const uint* Bb = ldsB + bi * 4096;
        half8 a0[4], a1[4];
#pragma unroll
        for (int i = 0; i < 4; ++i) FRAG(Ab, wr * 64 + i * 16 + lr, a0[i], a1[i]);
        __builtin_amdgcn_s_setprio(1);             // T5: favor MFMA wave
#pragma unroll
        for (int j = 0; j < 4; ++j) {
            half8 b0, b1;
            FRAG(Bb, wc * 64 + j * 16 + lr, b0, b1);
#pragma unroll
            for (int i = 0; i < 4; ++i) {
                acc0[i][j] = __builtin_amdgcn_mfma_f32_16x16x32_f16(a0[i], b0, acc0[i][j], 0, 0, 0);
                acc1[i][j] = __builtin_amdgcn_mfma_f32_16x16x32_f16(a1[i], b0, acc1[i][j], 0, 0, 0);
                acc1[i][j] = __builtin_amdgcn_mfma_f32_16x16x32_f16(a0[i], b1, acc1[i][j], 0, 0, 0);
            }
        }
        __builtin_amdgcn_s_setprio(0);
    };

    STAGE(r0, 0);
    if (nr > 1) STAGE(r0 + 1, 1);
    __builtin_amdgcn_sched_barrier(0);
    if (nr > 1) asm volatile("s_waitcnt vmcnt(%0)" :: "i"(NV) : "memory");
    else        asm volatile("s_waitcnt vmcnt(0)"  ::: "memory");
    __builtin_amdgcn_s_barrier();
    __builtin_amdgcn_sched_barrier(0);

    int bi = 0;
    for (int t = 0; t < nr; ++t) {
        COMPUTE(bi);
        if (t + 1 < nr) {
            __builtin_amdgcn_sched_barrier(0);
            __builtin_amdgcn_s_barrier();          // all waves done reading bi
            __builtin_amdgcn_sched_barrier(0);
            if (t + 2 < nr) {
                STAGE(r0 + t + 2, bi);
                __builtin_amdgcn_sched_barrier(0);
                asm volatile("s_waitcnt vmcnt(%0)" :: "i"(NV) : "memory");
            } else {
                asm volatile("s_waitcnt vmcnt(0)" ::: "memory");
            }
            __builtin_amdgcn_s_barrier();          // t+1 data visible
            __builtin_amdgcn_sched_barrier(0);
            bi ^= 1;
        }
    }

    float* Pk = P + (size_t)ks * M * N;
#pragma unroll
    for (int j = 0; j < 4; ++j) {
        const int n = n0 + wc * 64 + j * 16 + lr;
#pragma unroll
        for (int i = 0; i < 4; ++i) {
            const int mb = m0 + wr * 64 + i * 16 + kq * 4;
#pragma unroll
            for (int r = 0; r < 4; ++r)
                Pk[(size_t)(mb + r) * N + n] = acc0[i][j][r] + 0x1p-12f * acc1[i][j][r];
        }
    }
}

// ---------------------------------------------------------------------------
// Standalone GEMM wrapper (encoder / decoder prologue)
// ---------------------------------------------------------------------------
__global__ __launch_bounds__(256, 2) void gemm_pk4(
    const uint* __restrict__ A1, int K1, const uint* __restrict__ B1,
    const uint* __restrict__ A2, int K2, const uint* __restrict__ B2,
    float* __restrict__ P, int M, int N, int GM, int GN, int KS)
{
    __shared__ uint ldsA[2 * 4096];
    __shared__ uint ldsB[2 * 4096];
    gemm_body(ldsA, ldsB, A1, K1, B1, A2, K2, B2, P, M, N, GM, GN, KS, blockIdx.x);
}

// ---------------------------------------------------------------------------
// Fused decoder work (grid 640):
//   bid <  512 -> h-GEMM(h_t -> hparts, KS=4, nr=16)   [if doH]
//   512-639    -> ro-GEMM(h_t -> ropar, KS=4, nr=16)   (duration-matched)
// Both only READ h_t (pipelined dataflow verified r9/r12).
// ---------------------------------------------------------------------------
__global__ __launch_bounds__(256, 2) void dec_work(
    const uint* __restrict__ hcur, const uint* __restrict__ pdWhh,
    const uint* __restrict__ proW,
    float* __restrict__ hparts, float* __restrict__ ropar, int doH)
{
    __shared__ uint ldsA[2 * 4096];
    __shared__ uint ldsB[2 * 4096];
    const int bid = blockIdx.x;
    if (bid < 512) {
        if (!doH) return;
        gemm_body(ldsA, ldsB, nullptr, 0, nullptr, hcur, Hsz, pdWhh,
                  hparts, Bsz, Hsz, 8, 16, 4, bid);
    } else {
        gemm_body(ldsA, ldsB, nullptr, 0, nullptr, hcur, Hsz, proW,
                  ropar, Bsz, Isz, 8, 4, 4, bid - 512);
    }
}

// ---------------------------------------------------------------------------
// Combine 4 h-partials + biases, tanh, split-pack (PLANE layout)
// ---------------------------------------------------------------------------
__device__ __forceinline__ void combine_dev(
    const float* __restrict__ P, const float* __restrict__ b1,
    const float* __restrict__ b2, uint* __restrict__ hout, int cb)
{
    const int i0 = (cb * 256 + threadIdx.x) * 8;
    float s[8];
#pragma unroll
    for (int e = 0; e < 8; ++e) s[e] = 0.f;
#pragma unroll
    for (int p = 0; p < 4; ++p) {
        float4 a = *(const float4*)(P + (size_t)p * MNh + i0);
        float4 b = *(const float4*)(P + (size_t)p * MNh + i0 + 4);
        s[0] += a.x; s[1] += a.y; s[2] += a.z; s[3] += a.w;
        s[4] += b.x; s[5] += b.y; s[6] += b.z; s[7] += b.w;
    }
    const int n = i0 & (Hsz - 1);
    float t[8];
#pragma unroll
    for (int e = 0; e < 8; ++e) t[e] = tanhf(s[e] + b1[n + e] + b2[n + e]);
    uint lo4[4], hi4[4];
#pragma unroll
    for (int q = 0; q < 4; ++q) split_pair(t[2*q], t[2*q+1], lo4[q], hi4[q]);
    // chunk = 32 elements; lo-plane uints [0,16), hi-plane uints [16,32)
    uint* base = hout + ((i0 >> 5) << 5);
    const int eo = (i0 & 31) >> 1;     // 0,4,8,12
    *(uint4*)(base + eo)      = *(uint4*)lo4;
    *(uint4*)(base + 16 + eo) = *(uint4*)hi4;
}

__global__ __launch_bounds__(256) void combine_h4(
    const float* __restrict__ P, const float* __restrict__ b1,
    const float* __restrict__ b2, uint* __restrict__ hout)
{
    combine_dev(P, b1, b2, hout, blockIdx.x);
}

// ---------------------------------------------------------------------------
// log_softmax over Isz=512 (rob + NPART partials), argmax==2, done-latch
// ---------------------------------------------------------------------------
template<int NPART>
__device__ __forceinline__ void softmax_dev(
    const float* __restrict__ parts, const float* __restrict__ rob,
    float* __restrict__ done, float* __restrict__ out, int b)
{
    const int tid = threadIdx.x;
    const size_t S = (size_t)BI;
    const float* row = parts + (size_t)b * Isz;

    float v0, v1;
    if (NPART == 1) { v0 = row[tid]; v1 = row[tid + 256]; }
    else {
        v0 = rob[tid]; v1 = rob[tid + 256];
#pragma unroll
        for (int p = 0; p < NPART; ++p) { v0 += row[p*S + tid]; v1 += row[p*S + tid + 256]; }
    }

    float mv; int mi;
    if (v0 >= v1) { mv = v0; mi = tid; } else { mv = v1; mi = tid + 256; }
#pragma unroll
    for (int off = 32; off; off >>= 1) {
        float ov = __shfl_xor(mv, off);
        int   oi = __shfl_xor(mi, off);
        if (ov > mv || (ov == mv && oi < mi)) { mv = ov; mi = oi; }
    }
    __shared__ float smv[4];
    __shared__ int   smi[4];
    __shared__ float sdone;
    const int wid = tid >> 6, lane = tid & 63;
    if (lane == 0) { smv[wid] = mv; smi[wid] = mi; }
    __syncthreads();
    if (tid == 0) {
        for (int w = 1; w < 4; ++w)
            if (smv[w] > smv[0] || (smv[w] == smv[0] && smi[w] < smi[0])) {
                smv[0] = smv[w]; smi[0] = smi[w];
            }
        float z = (smi[0] == 2) ? 1.f : 0.f;
        float dn = fmaxf(done[b], z);
        done[b] = dn;
        sdone = dn;
    }
    __syncthreads();
    mv = smv[0];

    float s = expf(v0 - mv) + expf(v1 - mv);
#pragma unroll
    for (int off = 32; off; off >>= 1) s += __shfl_xor(s, off);
    __shared__ float ssum[4];
    if (lane == 0) ssum[wid] = s;
    __syncthreads();
    if (tid == 0) ssum[0] = ssum[0] + ssum[1] + ssum[2] + ssum[3];
    __syncthreads();
    const float ls = logf(ssum[0]);

    float* orow = out + (size_t)b * Isz;
    if (sdone > 0.5f) {
        orow[tid]       = (tid == 0) ? 1.f : 0.f;
        orow[tid + 256] = 0.f;
    } else {
        orow[tid]       = v0 - mv - ls;
        orow[tid + 256] = v1 - mv - ls;
    }
}

// Fused decoder finish: bid<1024 -> combine h_{t+1}; bid>=1024 -> softmax
__global__ __launch_bounds__(256) void dec_fin(
    const float* __restrict__ hparts, const float* __restrict__ dbih,
    const float* __restrict__ dbhh, uint* __restrict__ hout,
    const float* __restrict__ ropar, const float* __restrict__ rob,
    float* __restrict__ done, float* __restrict__ out, int doH)
{
    const int bid = blockIdx.x;
    if (bid < 1024) {
        if (doH) combine_dev(hparts, dbih, dbhh, hout, bid);
    } else {
        softmax_dev<4>(ropar, rob, done, out, bid - 1024);
    }
}

// Fallback softmax (single partial)
__global__ __launch_bounds__(256) void logsoftmax_done1(
    const float* __restrict__ logits, const float* __restrict__ rob,
    float* __restrict__ done, float* __restrict__ out)
{
    softmax_dev<1>(logits, rob, done, out, blockIdx.x);
}

// ---------------------------------------------------------------------------
// f32 -> PLANE-layout packed split (verified r15)
// ---------------------------------------------------------------------------
__global__ __launch_bounds__(256) void split_pack2_k(
    const float* __restrict__ s, uint* __restrict__ d, int n)
{
    for (int i = blockIdx.x * 256 + threadIdx.x; i < n; i += gridDim.x * 256) {
        const int c = i >> 5, j = i & 31;
        const int kb = c << 5;
        uint v;
        if (j < 16) {
            const int k = kb + (j << 1);
            _Float16 a0 = (_Float16)s[k], a1 = (_Float16)s[k + 1];
            v = (uint)__builtin_bit_cast(ushort, a0) |
                ((uint)__builtin_bit_cast(ushort, a1) << 16);
        } else {
            const int k = kb + ((j - 16) << 1);
            float f0 = s[k], f1 = s[k + 1];
            _Float16 b0 = (_Float16)((f0 - (float)(_Float16)f0) * 4096.f);
            _Float16 b1 = (_Float16)((f1 - (float)(_Float16)f1) * 4096.f);
            v = (uint)__builtin_bit_cast(ushort, b0) |
                ((uint)__builtin_bit_cast(ushort, b1) << 16);
        }
        d[i] = v;
    }
}

// ===========================================================================
// FALLBACK PATH (tiny ws): reg-staged split-f16 GEMM, fp32 B (unchanged)
// ===========================================================================
#define SWZ(row, kk) (((row) * 4 + ((kk) ^ (((row) >> 1) & 3))) * 8)

template<int BM, int BN, int WR, int WC, int MP, int NP, bool TANH, bool PACKOUT>
__global__ __launch_bounds__(WR*WC*64) void gemm_sp(
    const float* __restrict__ A1, int K1, const void* __restrict__ B1,
    const uint*  __restrict__ A2, int K2, const void* __restrict__ B2,
    int b_f32,
    const float* __restrict__ bias1, const float* __restrict__ bias2,
    void* __restrict__ C, int M, int N)
{
    constexpr int NT  = WR * WC * 64;
    constexpr int AUP = BM * 4 / NT;
    constexpr int BUP = BN * 4 / NT;

    __shared__ __align__(16) _Float16 As0[BM*32], As1[BM*32];
    __shared__ __align__(16) _Float16 Bs0[BN*32], Bs1[BN*32];

    const int tid  = threadIdx.x;
    const int wid  = tid >> 6, lane = tid & 63;
    const int wrow = wid / WC, wcol = wid % WC;
    const int kq   = lane >> 4, lr = lane & 15;
    const int m0   = blockIdx.y * BM;
    const int n0   = blockIdx.x * BN;

    int aum[AUP], auk[AUP]; _Float16 *aw0[AUP], *aw1[AUP];
#pragma unroll
    for (int p = 0; p < AUP; ++p) {
        int u = tid + p * NT; aum[p] = u >> 2; auk[p] = u & 3;
        int o = SWZ(aum[p], auk[p]); aw0[p] = As0 + o; aw1[p] = As1 + o;
    }
    int bun[BUP], buk[BUP]; _Float16 *bw0[BUP], *bw1[BUP];
#pragma unroll
    for (int p = 0; p < BUP; ++p) {
        int u = tid + p * NT; bun[p] = u >> 2; buk[p] = u & 3;
        int o = SWZ(bun[p], buk[p]); bw0[p] = Bs0 + o; bw1[p] = Bs1 + o;
    }
    int aoff[MP], boff[NP];
#pragma unroll
    for (int i = 0; i < MP; ++i) { int m = wrow*(MP*16) + i*16 + lr; aoff[i] = SWZ(m, kq); }
#pragma unroll
    for (int j = 0; j < NP; ++j) { int n = wcol*(NP*16) + j*16 + lr; boff[j] = SWZ(n, kq); }

    f32x4 acc0[MP][NP] = {}; f32x4 acc1[MP][NP] = {};

    const int R = (K1 + K2) / 32;

    auto issue = [&](int rd, U8* aR, U8* bR) {
        const bool ph1 = (rd * 32) < K1;
        const int  kl  = ph1 ? rd * 32 : rd * 32 - K1;
        const int  Ka  = ph1 ? K1 : K2;
        const uint* Ap = ph1 ? (const uint*)A1 : A2;
        const uint* Bp = (const uint*)(ph1 ? B1 : B2);
#pragma unroll
        for (int p = 0; p < AUP; ++p)
            aR[p] = ld8(Ap + (size_t)(m0 + aum[p]) * Ka + kl + auk[p] * 8);
#pragma unroll
        for (int p = 0; p < BUP; ++p)
            bR[p] = ld8(Bp + (size_t)(n0 + bun[p]) * Ka + kl + buk[p] * 8);
    };

    auto stage = [&](U8* aR, U8* bR, bool aF32) {
#pragma unroll
        for (int p = 0; p < AUP; ++p) {
            half8 lo, hi;
            if (aF32) split8(aR[p], lo, hi); else unpack8(aR[p], lo, hi);
            *(half8*)aw0[p] = lo; *(half8*)aw1[p] = hi;
        }
#pragma unroll
        for (int p = 0; p < BUP; ++p) {
            half8 lo, hi;
            if (b_f32) split8(bR[p], lo, hi); else unpack8(bR[p], lo, hi);
            *(half8*)bw0[p] = lo; *(half8*)bw1[p] = hi;
        }
    };

    auto compute = [&]() {
        half8 a0[MP], a1[MP], b0[NP], b1[NP];
#pragma unroll
        for (int i = 0; i < MP; ++i) {
            a0[i] = *(const half8*)(As0 + aoff[i]);
            a1[i] = *(const half8*)(As1 + aoff[i]);
        }
#pragma unroll
        for (int j = 0; j < NP; ++j) {
            b0[j] = *(const half8*)(Bs0 + boff[j]);
            b1[j] = *(const half8*)(Bs1 + boff[j]);
        }
#pragma unroll
        for (int i = 0; i < MP; ++i)
#pragma unroll
            for (int j = 0; j < NP; ++j) {
                acc0[i][j] = __builtin_amdgcn_mfma_f32_16x16x32_f16(a0[i], b0[j], acc0[i][j], 0, 0, 0);
                acc1[i][j] = __builtin_amdgcn_mfma_f32_16x16x32_f16(a1[i], b0[j], acc1[i][j], 0, 0, 0);
                acc1[i][j] = __builtin_amdgcn_mfma_f32_16x16x32_f16(a0[i], b1[j], acc1[i][j], 0, 0, 0);
            }
    };

    U8 aA[AUP], bA[BUP], aB[AUP], bB[BUP];
    issue(0, aA, bA);
    for (int rd = 0; rd < R; rd += 2) {
        if (rd + 1 < R) issue(rd + 1, aB, bB);
        stage(aA, bA, (rd * 32) < K1);
        __syncthreads();
        compute();
        __syncthreads();
        if (rd + 1 < R) {
            if (rd + 2 < R) issue(rd + 2, aA, bA);
            stage(aB, bB, ((rd + 1) * 32) < K1);
            __syncthreads();
            compute();
            __syncthreads();
        }
    }

#pragma unroll
    for (int j = 0; j < NP; ++j) {
        const int n = n0 + wcol*(NP*16) + j*16 + lr;
        float bb = bias1 ? bias1[n] : 0.f;
        if (bias2) bb += bias2[n];
#pragma unroll
        for (int i = 0; i < MP; ++i) {
            const int mb = m0 + wrow*(MP*16) + i*16 + kq*4;
#pragma unroll
            for (int r = 0; r < 4; ++r) {
                float val = acc0[i][j][r] + 0x1p-12f * acc1[i][j][r] + bb;
                if (TANH) val = tanhf(val);
                if (PACKOUT)
                    ((uint*)C)[(size_t)(mb + r) * N + n] = pack_split(val);
                else
                    ((float*)C)[(size_t)(mb + r) * N + n] = val;
            }
        }
    }
}

// ---------------------------------------------------------------------------
extern "C" void kernel_launch(void* const* d_in, const int* in_sizes, int n_in,
                              void* d_out, int out_size, void* d_ws, size_t ws_size,
                              hipStream_t stream)
{
    const float* x    = (const float*)d_in[0];
    const float* eWih = (const float*)d_in[1];
    const float* eWhh = (const float*)d_in[2];
    const float* ebih = (const float*)d_in[3];
    const float* ebhh = (const float*)d_in[4];
    const float* dWhh = (const float*)d_in[6];
    const float* dbih = (const float*)d_in[7];
    const float* dbhh = (const float*)d_in[8];
    const float* roW  = (const float*)d_in[9];
    const float* rob  = (const float*)d_in[10];
    float* out = (float*)d_out;

    const size_t sz_pWih = (size_t)Hsz * Isz * 4;        //  4 MB
    const size_t sz_pWhh = (size_t)Hsz * Hsz * 4;        // 16 MB
    const size_t sz_proW = (size_t)Isz * Hsz * 4;        //  4 MB
    const size_t sz_h    = (size_t)MNh * 4;              //  8 MB packed
    const size_t sz_hp   = (size_t)4 * MNh * 4;          // 32 MB h partials
    const size_t sz_rp   = (size_t)4 * BI * 4;           //  8 MB ro partials
    const size_t sz_done = (size_t)Bsz * 4;
    const size_t sz_px2  = (size_t)Tenc * BI * 4;        // 136 MB
    const size_t sz_slot = (size_t)BI * 4;               //   2 MB

    const size_t base = sz_pWih + 2*sz_pWhh + sz_proW + 2*sz_h + sz_hp + sz_rp + sz_done;
    const int mode = (ws_size >= base + sz_px2) ? 2
                   : (ws_size >= base + sz_slot) ? 1 : 0;

    char* ws = (char*)d_ws;

    if (mode >= 1) {
        size_t off = 0;
        uint* pWih   = (uint*)(ws + off); off += sz_pWih;
        uint* pWhh   = (uint*)(ws + off); off += sz_pWhh;
        uint* pdWhh  = (uint*)(ws + off); off += sz_pWhh;
        uint* proW   = (uint*)(ws + off); off += sz_proW;
        uint* hA     = (uint*)(ws + off); off += sz_h;
        uint* hB     = (uint*)(ws + off); off += sz_h;
        float* hparts= (float*)(ws + off); off += sz_hp;
        float* ropar = (float*)(ws + off); off += sz_rp;
        float* done  = (float*)(ws + off); off += sz_done;
        uint* px     = (uint*)(ws + off);   // mode2: 65 steps; mode1: 1 slot

        split_pack2_k<<<dim3(1024), dim3(256), 0, stream>>>(eWih, pWih,  Hsz*Isz);
        split_pack2_k<<<dim3(2048), dim3(256), 0, stream>>>(eWhh, pWhh,  Hsz*Hsz);
        split_pack2_k<<<dim3(2048), dim3(256), 0, stream>>>(dWhh, pdWhh, Hsz*Hsz);
        split_pack2_k<<<dim3(1024), dim3(256), 0, stream>>>(roW,  proW,  Isz*Hsz);
        if (mode == 2)
            split_pack2_k<<<dim3(2048), dim3(256), 0, stream>>>(x, px, Tenc*BI);

        hipMemsetAsync(hA,   0, sz_h,    stream);
        hipMemsetAsync(done, 0, sz_done, stream);

        uint* h[2] = { hA, hB };
        int cur = 0;
        // ---- encoder: K = 512 + 2048, KS=4 -> 512 blocks (2/CU) ----
        for (int t = 0; t < Tenc; ++t) {
            const uint* xs;
            if (mode == 2) xs = px + (size_t)t * BI;
            else {
                split_pack2_k<<<dim3(512), dim3(256), 0, stream>>>(
                    x + (size_t)t * BI, px, BI);
                xs = px;
            }
            gemm_pk4<<<dim3(512), dim3(256), 0, stream>>>(
                xs, Isz, pWih, h[cur], Hsz, pWhh,
                hparts, Bsz, Hsz, 8, 16, 4);
            combine_h4<<<dim3(1024), dim3(256), 0, stream>>>(
                hparts, ebih, ebhh, h[cur ^ 1]);
            cur ^= 1;
        }
        // ---- decoder prologue: h_1 = tanh(bias + h_enc @ Whh^T) ----
        gemm_pk4<<<dim3(512), dim3(256), 0, stream>>>(
            nullptr, 0, nullptr, h[cur], Hsz, pdWhh,
            hparts, Bsz, Hsz, 8, 16, 4);
        combine_h4<<<dim3(1024), dim3(256), 0, stream>>>(
            hparts, dbih, dbhh, h[cur ^ 1]);
        cur ^= 1;
        // ---- decoder: 64 steps x 2 fused launches ----
        for (int t = 0; t < Tdec; ++t) {
            const int doH = (t + 1 < Tdec) ? 1 : 0;
            dec_work<<<dim3(640), dim3(256), 0, stream>>>(
                h[cur], pdWhh, proW, hparts, ropar, doH);
            dec_fin<<<dim3(2048), dim3(256), 0, stream>>>(
                hparts, dbih, dbhh, h[cur ^ 1],
                ropar, rob, done, out + (size_t)t * BI, doH);
            cur ^= 1;
        }
        return;
    }

    // ================= fallback path (tiny ws) =================
    {
        const size_t sz_lg = (size_t)BI * 4;
        size_t off = 0;
        uint*  hA     = (uint*)(ws + off); off += sz_h;
        uint*  hB     = (uint*)(ws + off); off += sz_h;
        float* logits = (float*)(ws + off); off += sz_lg;
        float* done   = (float*)(ws + off);

        hipMemsetAsync(hA, 0, sz_h, stream);
        hipMemsetAsync(done, 0, sz_done, stream);

        uint* h[2] = { hA, hB };
        const dim3 blk(256);
        const dim3 grid_h(Hsz / 128, Bsz / 64);
        const dim3 grid_ro(Isz / 64, Bsz / 64);

        int cur = 0;
        for (int t = 0; t < Tenc; ++t) {
            gemm_sp<64, 128, 2, 2, 2, 4, true, true><<<grid_h, blk, 0, stream>>>(
                x + (size_t)t * BI, Isz, eWih,
                h[cur], Hsz, eWhh, 1,
                ebih, ebhh, h[cur ^ 1], Bsz, Hsz);
            cur ^= 1;
        }
        for (int t = 0; t < Tdec; ++t) {
            gemm_sp<64, 128, 2, 2, 2, 4, true, true><<<grid_h, blk, 0, stream>>>(
                nullptr, 0, nullptr, h[cur], Hsz, dWhh, 1,
                dbih, dbhh, h[cur ^ 1], Bsz, Hsz);
            cur ^= 1;
            gemm_sp<64, 64, 2, 2, 2, 2, false, false><<<grid_ro, blk, 0, stream>>>(
                nullptr, 0, nullptr, h[cur], Hsz, roW, 1,
                rob, nullptr, logits, Bsz, Isz);
            logsoftmax_done1<<<dim3(Bsz), dim3(256), 0, stream>>>(
                logits, rob, done, out + (size_t)t * BI);
        }
    }
}

// Round 18
// 6178.735 us; speedup vs baseline: 1.1504x; 1.0014x over previous
//
#include <hip/hip_runtime.h>
#include <math.h>

// Problem constants (VanillaRNN: T=129, B=1024, I=512, H=2048, k=63)
constexpr int Bsz  = 1024;
constexpr int Isz  = 512;
constexpr int Hsz  = 2048;
constexpr int Tenc = 65;   // k+2 encoder steps
constexpr int Tdec = 64;   // k+1 decoder steps
constexpr int BI   = Bsz * Isz;     // 524288
constexpr int MNh  = Bsz * Hsz;     // 2097152

typedef _Float16 half8 __attribute__((ext_vector_type(8)));
typedef float    f32x4 __attribute__((ext_vector_type(4)));
typedef unsigned int uint;
typedef unsigned short ushort;

// ---- split-f16 helpers ----------------------------------------------------
__device__ inline uint pack_split(float v) {            // element-interleaved
    _Float16 a0 = (_Float16)v;
    float r = (v - (float)a0) * 4096.f;
    _Float16 a1 = (_Float16)r;
    return ((uint)__builtin_bit_cast(ushort, a1) << 16) | __builtin_bit_cast(ushort, a0);
}
// pair -> (lo0|lo1<<16 , hi0|hi1<<16)   (plane layout)
__device__ inline void split_pair(float v0, float v1, uint& lo, uint& hi) {
    _Float16 a0 = (_Float16)v0, a1 = (_Float16)v1;
    _Float16 b0 = (_Float16)((v0 - (float)a0) * 4096.f);
    _Float16 b1 = (_Float16)((v1 - (float)a1) * 4096.f);
    lo = (uint)__builtin_bit_cast(ushort, a0) | ((uint)__builtin_bit_cast(ushort, a1) << 16);
    hi = (uint)__builtin_bit_cast(ushort, b0) | ((uint)__builtin_bit_cast(ushort, b1) << 16);
}

struct U8 { uint4 a, b; };
__device__ inline U8 ld8(const uint* __restrict__ p) {
    U8 r; r.a = *(const uint4*)p; r.b = *(const uint4*)(p + 4); return r;
}

// (fallback path helpers: element-interleaved format)
__device__ inline void split8(const U8& v, half8& lo, half8& hi) {
    union { uint4 u; float f[4]; } A, B;
    A.u = v.a; B.u = v.b;
    float x[8] = {A.f[0], A.f[1], A.f[2], A.f[3], B.f[0], B.f[1], B.f[2], B.f[3]};
#pragma unroll
    for (int e = 0; e < 8; ++e) {
        _Float16 a0 = (_Float16)x[e];
        float r = (x[e] - (float)a0) * 4096.f;
        lo[e] = a0; hi[e] = (_Float16)r;
    }
}
__device__ inline void unpack8(const U8& v, half8& lo, half8& hi) {
    union { uint u[4]; half8 h; } L, H;
    uint w[8] = {v.a.x, v.a.y, v.a.z, v.a.w, v.b.x, v.b.y, v.b.z, v.b.w};
#pragma unroll
    for (int q = 0; q < 4; ++q) {
        L.u[q] = __builtin_amdgcn_perm(w[2*q+1], w[2*q], 0x05040100u);
        H.u[q] = __builtin_amdgcn_perm(w[2*q+1], w[2*q], 0x07060302u);
    }
    lo = L.h; hi = H.h;
}

// async global(16B) -> LDS, per-lane global src, wave-uniform LDS base
__device__ __forceinline__ void gll16(const uint* g, uint* l) {
    __builtin_amdgcn_global_load_lds(
        (const __attribute__((address_space(1))) void*)(uintptr_t)g,
        (__attribute__((address_space(3))) void*)(unsigned int)(uintptr_t)l,
        16, 0, 0);
}

// ===========================================================================
// Split-K split-f16 GEMM body — PLANE-INTERLEAVED layout (verified r15/r17)
// + T5 s_setprio around the MFMA cluster.
// Tile 128x128, BK=32, 4 waves (2x2), wave-tile 64x64, 2-buffer LDS
// ping-pong (64 KiB -> 2 blocks/CU), global_load_lds staging, counted vmcnt.
// LDS: unit u of a row stored at position u^(row&7); inverse swizzle is
// pre-applied to the GLOBAL source address (LDS dest stays linear).
// XCD-stable decode: n-strip pinned to an XCD (weight slice L2-resident).
// ===========================================================================
__device__ __forceinline__ void gemm_body(
    uint* ldsA, uint* ldsB,
    const uint* A1, int K1, const uint* B1,
    const uint* A2, int K2, const uint* B2,
    float* P, int M, int N, int GM, int GN, int KS, int bid)
{
    constexpr int NV = 8;            // gll16 per STAGE per thread (4 A + 4 B)
    const int tid  = threadIdx.x;
    const int wid  = tid >> 6, lane = tid & 63;
    const int wr   = wid >> 1, wc = wid & 1;
    const int kq   = lane >> 4, lr = lane & 15;

    // ---- XCD-stable block decode: n-strip pinned to an XCD ----
    const int xcd = bid & 7, g = bid >> 3;
    int n_b, m_b, ks;
    const int spx = GN >> 3;
    if (spx > 0) {
        n_b = xcd * spx + (g % spx);
        int r = g / spx; m_b = r % GM; ks = r / GM;
    } else {
        const int xpn = 8 / GN;
        n_b = xcd / xpn;
        int r = g * xpn + (xcd % xpn); m_b = r % GM; ks = r / GM;
    }
    const int m0 = m_b * 128, n0 = n_b * 128;

    int offA1[4], offA2[4], offB1[4], offB2[4];
#pragma unroll
    for (int q = 0; q < 4; ++q) {
        int U = q * 256 + tid, row = U >> 3, us = U & 7;
        int u = us ^ (row & 7);                   // inverse read-swizzle
        offA1[q] = (m0 + row) * K1 + u * 4;
        offA2[q] = (m0 + row) * K2 + u * 4;
        offB1[q] = (n0 + row) * K1 + u * 4;
        offB2[q] = (n0 + row) * K2 + u * 4;
    }
    const int ldsbase = wid * 256;

    const int R1 = K1 / 32;
    const int R  = (K1 + K2) / 32;
    const int nr = R / KS;
    const int r0 = ks * nr;

    auto STAGE = [&](int r, int bi) {
        uint* Ab = ldsA + bi * 4096;
        uint* Bb = ldsB + bi * 4096;
        const bool ph1 = r < R1;
        const int kl = (ph1 ? r : r - R1) * 32;
        const uint* As = ph1 ? A1 : A2;
        const uint* Bs = ph1 ? B1 : B2;
#pragma unroll
        for (int q = 0; q < 4; ++q)
            gll16(As + (ph1 ? offA1[q] : offA2[q]) + kl, Ab + q * 1024 + ldsbase);
#pragma unroll
        for (int q = 0; q < 4; ++q)
            gll16(Bs + (ph1 ? offB1[q] : offB2[q]) + kl, Bb + q * 1024 + ldsbase);
    };

    f32x4 acc0[4][4] = {}; f32x4 acc1[4][4] = {};

    // direct half8 fragment loads: lo = unit kq, hi = unit kq+4 (swizzled)
    auto FRAG = [&](const uint* buf, int row, half8& lo, half8& hi) {
        const int b = row * 8, s = row & 7;
        lo = *(const half8*)(buf + (b + (kq ^ s)) * 4);
        hi = *(const half8*)(buf + (b + ((kq + 4) ^ s)) * 4);
    };

    auto COMPUTE = [&](int bi) {
        const uint* Ab = ldsA + bi * 4096;
        const uint* Bb = ldsB + bi * 4096;
        half8 a0[4], a1[4];
#pragma unroll
        for (int i = 0; i < 4; ++i) FRAG(Ab, wr * 64 + i * 16 + lr, a0[i], a1[i]);
        __builtin_amdgcn_s_setprio(1);             // T5: favor MFMA wave
#pragma unroll
        for (int j = 0; j < 4; ++j) {
            half8 b0, b1;
            FRAG(Bb, wc * 64 + j * 16 + lr, b0, b1);
#pragma unroll
            for (int i = 0; i < 4; ++i) {
                acc0[i][j] = __builtin_amdgcn_mfma_f32_16x16x32_f16(a0[i], b0, acc0[i][j], 0, 0, 0);
                acc1[i][j] = __builtin_amdgcn_mfma_f32_16x16x32_f16(a1[i], b0, acc1[i][j], 0, 0, 0);
                acc1[i][j] = __builtin_amdgcn_mfma_f32_16x16x32_f16(a0[i], b1, acc1[i][j], 0, 0, 0);
            }
        }
        __builtin_amdgcn_s_setprio(0);
    };

    STAGE(r0, 0);
    if (nr > 1) STAGE(r0 + 1, 1);
    __builtin_amdgcn_sched_barrier(0);
    if (nr > 1) asm volatile("s_waitcnt vmcnt(%0)" :: "i"(NV) : "memory");
    else        asm volatile("s_waitcnt vmcnt(0)"  ::: "memory");
    __builtin_amdgcn_s_barrier();
    __builtin_amdgcn_sched_barrier(0);

    int bi = 0;
    for (int t = 0; t < nr; ++t) {
        COMPUTE(bi);
        if (t + 1 < nr) {
            __builtin_amdgcn_sched_barrier(0);
            __builtin_amdgcn_s_barrier();          // all waves done reading bi
            __builtin_amdgcn_sched_barrier(0);
            if (t + 2 < nr) {
                STAGE(r0 + t + 2, bi);
                __builtin_amdgcn_sched_barrier(0);
                asm volatile("s_waitcnt vmcnt(%0)" :: "i"(NV) : "memory");
            } else {
                asm volatile("s_waitcnt vmcnt(0)" ::: "memory");
            }
            __builtin_amdgcn_s_barrier();          // t+1 data visible
            __builtin_amdgcn_sched_barrier(0);
            bi ^= 1;
        }
    }

    float* Pk = P + (size_t)ks * M * N;
#pragma unroll
    for (int j = 0; j < 4; ++j) {
        const int n = n0 + wc * 64 + j * 16 + lr;
#pragma unroll
        for (int i = 0; i < 4; ++i) {
            const int mb = m0 + wr * 64 + i * 16 + kq * 4;
#pragma unroll
            for (int r = 0; r < 4; ++r)
                Pk[(size_t)(mb + r) * N + n] = acc0[i][j][r] + 0x1p-12f * acc1[i][j][r];
        }
    }
}

// ---------------------------------------------------------------------------
// Standalone GEMM wrapper (encoder / decoder prologue)
// ---------------------------------------------------------------------------
__global__ __launch_bounds__(256, 2) void gemm_pk4(
    const uint* __restrict__ A1, int K1, const uint* __restrict__ B1,
    const uint* __restrict__ A2, int K2, const uint* __restrict__ B2,
    float* __restrict__ P, int M, int N, int GM, int GN, int KS)
{
    __shared__ uint ldsA[2 * 4096];
    __shared__ uint ldsB[2 * 4096];
    gemm_body(ldsA, ldsB, A1, K1, B1, A2, K2, B2, P, M, N, GM, GN, KS, blockIdx.x);
}

// ---------------------------------------------------------------------------
// Fused decoder work (grid 768):
//   bid <  512 -> h-GEMM(h_t -> hparts, KS=4, nr=16)   [if doH]  (wave 1)
//   512-767    -> ro-GEMM(h_t -> ropar, KS=8, nr=8)    (short backfill blocks)
// Both only READ h_t (pipelined dataflow verified r9/r12).
// ---------------------------------------------------------------------------
__global__ __launch_bounds__(256, 2) void dec_work(
    const uint* __restrict__ hcur, const uint* __restrict__ pdWhh,
    const uint* __restrict__ proW,
    float* __restrict__ hparts, float* __restrict__ ropar, int doH)
{
    __shared__ uint ldsA[2 * 4096];
    __shared__ uint ldsB[2 * 4096];
    const int bid = blockIdx.x;
    if (bid < 512) {
        if (!doH) return;
        gemm_body(ldsA, ldsB, nullptr, 0, nullptr, hcur, Hsz, pdWhh,
                  hparts, Bsz, Hsz, 8, 16, 4, bid);
    } else {
        gemm_body(ldsA, ldsB, nullptr, 0, nullptr, hcur, Hsz, proW,
                  ropar, Bsz, Isz, 8, 4, 8, bid - 512);
    }
}

// ---------------------------------------------------------------------------
// Combine 4 h-partials + biases, tanh, split-pack (PLANE layout)
// ---------------------------------------------------------------------------
__device__ __forceinline__ void combine_dev(
    const float* __restrict__ P, const float* __restrict__ b1,
    const float* __restrict__ b2, uint* __restrict__ hout, int cb)
{
    const int i0 = (cb * 256 + threadIdx.x) * 8;
    float s[8];
#pragma unroll
    for (int e = 0; e < 8; ++e) s[e] = 0.f;
#pragma unroll
    for (int p = 0; p < 4; ++p) {
        float4 a = *(const float4*)(P + (size_t)p * MNh + i0);
        float4 b = *(const float4*)(P + (size_t)p * MNh + i0 + 4);
        s[0] += a.x; s[1] += a.y; s[2] += a.z; s[3] += a.w;
        s[4] += b.x; s[5] += b.y; s[6] += b.z; s[7] += b.w;
    }
    const int n = i0 & (Hsz - 1);
    float t[8];
#pragma unroll
    for (int e = 0; e < 8; ++e) t[e] = tanhf(s[e] + b1[n + e] + b2[n + e]);
    uint lo4[4], hi4[4];
#pragma unroll
    for (int q = 0; q < 4; ++q) split_pair(t[2*q], t[2*q+1], lo4[q], hi4[q]);
    // chunk = 32 elements; lo-plane uints [0,16), hi-plane uints [16,32)
    uint* base = hout + ((i0 >> 5) << 5);
    const int eo = (i0 & 31) >> 1;     // 0,4,8,12
    *(uint4*)(base + eo)      = *(uint4*)lo4;
    *(uint4*)(base + 16 + eo) = *(uint4*)hi4;
}

__global__ __launch_bounds__(256) void combine_h4(
    const float* __restrict__ P, const float* __restrict__ b1,
    const float* __restrict__ b2, uint* __restrict__ hout)
{
    combine_dev(P, b1, b2, hout, blockIdx.x);
}

// ---------------------------------------------------------------------------
// log_softmax over Isz=512 (rob + NPART partials), argmax==2, done-latch
// ---------------------------------------------------------------------------
template<int NPART>
__device__ __forceinline__ void softmax_dev(
    const float* __restrict__ parts, const float* __restrict__ rob,
    float* __restrict__ done, float* __restrict__ out, int b)
{
    const int tid = threadIdx.x;
    const size_t S = (size_t)BI;
    const float* row = parts + (size_t)b * Isz;

    float v0, v1;
    if (NPART == 1) { v0 = row[tid]; v1 = row[tid + 256]; }
    else {
        v0 = rob[tid]; v1 = rob[tid + 256];
#pragma unroll
        for (int p = 0; p < NPART; ++p) { v0 += row[p*S + tid]; v1 += row[p*S + tid + 256]; }
    }

    float mv; int mi;
    if (v0 >= v1) { mv = v0; mi = tid; } else { mv = v1; mi = tid + 256; }
#pragma unroll
    for (int off = 32; off; off >>= 1) {
        float ov = __shfl_xor(mv, off);
        int   oi = __shfl_xor(mi, off);
        if (ov > mv || (ov == mv && oi < mi)) { mv = ov; mi = oi; }
    }
    __shared__ float smv[4];
    __shared__ int   smi[4];
    __shared__ float sdone;
    const int wid = tid >> 6, lane = tid & 63;
    if (lane == 0) { smv[wid] = mv; smi[wid] = mi; }
    __syncthreads();
    if (tid == 0) {
        for (int w = 1; w < 4; ++w)
            if (smv[w] > smv[0] || (smv[w] == smv[0] && smi[w] < smi[0])) {
                smv[0] = smv[w]; smi[0] = smi[w];
            }
        float z = (smi[0] == 2) ? 1.f : 0.f;
        float dn = fmaxf(done[b], z);
        done[b] = dn;
        sdone = dn;
    }
    __syncthreads();
    mv = smv[0];

    float s = expf(v0 - mv) + expf(v1 - mv);
#pragma unroll
    for (int off = 32; off; off >>= 1) s += __shfl_xor(s, off);
    __shared__ float ssum[4];
    if (lane == 0) ssum[wid] = s;
    __syncthreads();
    if (tid == 0) ssum[0] = ssum[0] + ssum[1] + ssum[2] + ssum[3];
    __syncthreads();
    const float ls = logf(ssum[0]);

    float* orow = out + (size_t)b * Isz;
    if (sdone > 0.5f) {
        orow[tid]       = (tid == 0) ? 1.f : 0.f;
        orow[tid + 256] = 0.f;
    } else {
        orow[tid]       = v0 - mv - ls;
        orow[tid + 256] = v1 - mv - ls;
    }
}

// Fused decoder finish: bid<1024 -> combine h_{t+1}; bid>=1024 -> softmax
__global__ __launch_bounds__(256) void dec_fin(
    const float* __restrict__ hparts, const float* __restrict__ dbih,
    const float* __restrict__ dbhh, uint* __restrict__ hout,
    const float* __restrict__ ropar, const float* __restrict__ rob,
    float* __restrict__ done, float* __restrict__ out, int doH)
{
    const int bid = blockIdx.x;
    if (bid < 1024) {
        if (doH) combine_dev(hparts, dbih, dbhh, hout, bid);
    } else {
        softmax_dev<8>(ropar, rob, done, out, bid - 1024);
    }
}

// Fallback softmax (single partial)
__global__ __launch_bounds__(256) void logsoftmax_done1(
    const float* __restrict__ logits, const float* __restrict__ rob,
    float* __restrict__ done, float* __restrict__ out)
{
    softmax_dev<1>(logits, rob, done, out, blockIdx.x);
}

// ---------------------------------------------------------------------------
// f32 -> PLANE-layout packed split (verified r15)
// ---------------------------------------------------------------------------
__global__ __launch_bounds__(256) void split_pack2_k(
    const float* __restrict__ s, uint* __restrict__ d, int n)
{
    for (int i = blockIdx.x * 256 + threadIdx.x; i < n; i += gridDim.x * 256) {
        const int c = i >> 5, j = i & 31;
        const int kb = c << 5;
        uint v;
        if (j < 16) {
            const int k = kb + (j << 1);
            _Float16 a0 = (_Float16)s[k], a1 = (_Float16)s[k + 1];
            v = (uint)__builtin_bit_cast(ushort, a0) |
                ((uint)__builtin_bit_cast(ushort, a1) << 16);
        } else {
            const int k = kb + ((j - 16) << 1);
            float f0 = s[k], f1 = s[k + 1];
            _Float16 b0 = (_Float16)((f0 - (float)(_Float16)f0) * 4096.f);
            _Float16 b1 = (_Float16)((f1 - (float)(_Float16)f1) * 4096.f);
            v = (uint)__builtin_bit_cast(ushort, b0) |
                ((uint)__builtin_bit_cast(ushort, b1) << 16);
        }
        d[i] = v;
    }
}

// ===========================================================================
// FALLBACK PATH (tiny ws): reg-staged split-f16 GEMM, fp32 B (unchanged)
// ===========================================================================
#define SWZ(row, kk) (((row) * 4 + ((kk) ^ (((row) >> 1) & 3))) * 8)

template<int BM, int BN, int WR, int WC, int MP, int NP, bool TANH, bool PACKOUT>
__global__ __launch_bounds__(WR*WC*64) void gemm_sp(
    const float* __restrict__ A1, int K1, const void* __restrict__ B1,
    const uint*  __restrict__ A2, int K2, const void* __restrict__ B2,
    int b_f32,
    const float* __restrict__ bias1, const float* __restrict__ bias2,
    void* __restrict__ C, int M, int N)
{
    constexpr int NT  = WR * WC * 64;
    constexpr int AUP = BM * 4 / NT;
    constexpr int BUP = BN * 4 / NT;

    __shared__ __align__(16) _Float16 As0[BM*32], As1[BM*32];
    __shared__ __align__(16) _Float16 Bs0[BN*32], Bs1[BN*32];

    const int tid  = threadIdx.x;
    const int wid  = tid >> 6, lane = tid & 63;
    const int wrow = wid / WC, wcol = wid % WC;
    const int kq   = lane >> 4, lr = lane & 15;
    const int m0   = blockIdx.y * BM;
    const int n0   = blockIdx.x * BN;

    int aum[AUP], auk[AUP]; _Float16 *aw0[AUP], *aw1[AUP];
#pragma unroll
    for (int p = 0; p < AUP; ++p) {
        int u = tid + p * NT; aum[p] = u >> 2; auk[p] = u & 3;
        int o = SWZ(aum[p], auk[p]); aw0[p] = As0 + o; aw1[p] = As1 + o;
    }
    int bun[BUP], buk[BUP]; _Float16 *bw0[BUP], *bw1[BUP];
#pragma unroll
    for (int p = 0; p < BUP; ++p) {
        int u = tid + p * NT; bun[p] = u >> 2; buk[p] = u & 3;
        int o = SWZ(bun[p], buk[p]); bw0[p] = Bs0 + o; bw1[p] = Bs1 + o;
    }
    int aoff[MP], boff[NP];
#pragma unroll
    for (int i = 0; i < MP; ++i) { int m = wrow*(MP*16) + i*16 + lr; aoff[i] = SWZ(m, kq); }
#pragma unroll
    for (int j = 0; j < NP; ++j) { int n = wcol*(NP*16) + j*16 + lr; boff[j] = SWZ(n, kq); }

    f32x4 acc0[MP][NP] = {}; f32x4 acc1[MP][NP] = {};

    const int R = (K1 + K2) / 32;

    auto issue = [&](int rd, U8* aR, U8* bR) {
        const bool ph1 = (rd * 32) < K1;
        const int  kl  = ph1 ? rd * 32 : rd * 32 - K1;
        const int  Ka  = ph1 ? K1 : K2;
        const uint* Ap = ph1 ? (const uint*)A1 : A2;
        const uint* Bp = (const uint*)(ph1 ? B1 : B2);
#pragma unroll
        for (int p = 0; p < AUP; ++p)
            aR[p] = ld8(Ap + (size_t)(m0 + aum[p]) * Ka + kl + auk[p] * 8);
#pragma unroll
        for (int p = 0; p < BUP; ++p)
            bR[p] = ld8(Bp + (size_t)(n0 + bun[p]) * Ka + kl + buk[p] * 8);
    };

    auto stage = [&](U8* aR, U8* bR, bool aF32) {
#pragma unroll
        for (int p = 0; p < AUP; ++p) {
            half8 lo, hi;
            if (aF32) split8(aR[p], lo, hi); else unpack8(aR[p], lo, hi);
            *(half8*)aw0[p] = lo; *(half8*)aw1[p] = hi;
        }
#pragma unroll
        for (int p = 0; p < BUP; ++p) {
            half8 lo, hi;
            if (b_f32) split8(bR[p], lo, hi); else unpack8(bR[p], lo, hi);
            *(half8*)bw0[p] = lo; *(half8*)bw1[p] = hi;
        }
    };

    auto compute = [&]() {
        half8 a0[MP], a1[MP], b0[NP], b1[NP];
#pragma unroll
        for (int i = 0; i < MP; ++i) {
            a0[i] = *(const half8*)(As0 + aoff[i]);
            a1[i] = *(const half8*)(As1 + aoff[i]);
        }
#pragma unroll
        for (int j = 0; j < NP; ++j) {
            b0[j] = *(const half8*)(Bs0 + boff[j]);
            b1[j] = *(const half8*)(Bs1 + boff[j]);
        }
#pragma unroll
        for (int i = 0; i < MP; ++i)
#pragma unroll
            for (int j = 0; j < NP; ++j) {
                acc0[i][j] = __builtin_amdgcn_mfma_f32_16x16x32_f16(a0[i], b0[j], acc0[i][j], 0, 0, 0);
                acc1[i][j] = __builtin_amdgcn_mfma_f32_16x16x32_f16(a1[i], b0[j], acc1[i][j], 0, 0, 0);
                acc1[i][j] = __builtin_amdgcn_mfma_f32_16x16x32_f16(a0[i], b1[j], acc1[i][j], 0, 0, 0);
            }
    };

    U8 aA[AUP], bA[BUP], aB[AUP], bB[BUP];
    issue(0, aA, bA);
    for (int rd = 0; rd < R; rd += 2) {
        if (rd + 1 < R) issue(rd + 1, aB, bB);
        stage(aA, bA, (rd * 32) < K1);
        __syncthreads();
        compute();
        __syncthreads();
        if (rd + 1 < R) {
            if (rd + 2 < R) issue(rd + 2, aA, bA);
            stage(aB, bB, ((rd + 1) * 32) < K1);
            __syncthreads();
            compute();
            __syncthreads();
        }
    }

#pragma unroll
    for (int j = 0; j < NP; ++j) {
        const int n = n0 + wcol*(NP*16) + j*16 + lr;
        float bb = bias1 ? bias1[n] : 0.f;
        if (bias2) bb += bias2[n];
#pragma unroll
        for (int i = 0; i < MP; ++i) {
            const int mb = m0 + wrow*(MP*16) + i*16 + kq*4;
#pragma unroll
            for (int r = 0; r < 4; ++r) {
                float val = acc0[i][j][r] + 0x1p-12f * acc1[i][j][r] + bb;
                if (TANH) val = tanhf(val);
                if (PACKOUT)
                    ((uint*)C)[(size_t)(mb + r) * N + n] = pack_split(val);
                else
                    ((float*)C)[(size_t)(mb + r) * N + n] = val;
            }
        }
    }
}

// ---------------------------------------------------------------------------
extern "C" void kernel_launch(void* const* d_in, const int* in_sizes, int n_in,
                              void* d_out, int out_size, void* d_ws, size_t ws_size,
                              hipStream_t stream)
{
    const float* x    = (const float*)d_in[0];
    const float* eWih = (const float*)d_in[1];
    const float* eWhh = (const float*)d_in[2];
    const float* ebih = (const float*)d_in[3];
    const float* ebhh = (const float*)d_in[4];
    const float* dWhh = (const float*)d_in[6];
    const float* dbih = (const float*)d_in[7];
    const float* dbhh = (const float*)d_in[8];
    const float* roW  = (const float*)d_in[9];
    const float* rob  = (const float*)d_in[10];
    float* out = (float*)d_out;

    const size_t sz_pWih = (size_t)Hsz * Isz * 4;        //  4 MB
    const size_t sz_pWhh = (size_t)Hsz * Hsz * 4;        // 16 MB
    const size_t sz_proW = (size_t)Isz * Hsz * 4;        //  4 MB
    const size_t sz_h    = (size_t)MNh * 4;              //  8 MB packed
    const size_t sz_hp   = (size_t)4 * MNh * 4;          // 32 MB h partials
    const size_t sz_rp   = (size_t)8 * BI * 4;           // 16 MB ro partials
    const size_t sz_done = (size_t)Bsz * 4;
    const size_t sz_px2  = (size_t)Tenc * BI * 4;        // 136 MB
    const size_t sz_slot = (size_t)BI * 4;               //   2 MB

    const size_t base = sz_pWih + 2*sz_pWhh + sz_proW + 2*sz_h + sz_hp + sz_rp + sz_done;
    const int mode = (ws_size >= base + sz_px2) ? 2
                   : (ws_size >= base + sz_slot) ? 1 : 0;

    char* ws = (char*)d_ws;

    if (mode >= 1) {
        size_t off = 0;
        uint* pWih   = (uint*)(ws + off); off += sz_pWih;
        uint* pWhh   = (uint*)(ws + off); off += sz_pWhh;
        uint* pdWhh  = (uint*)(ws + off); off += sz_pWhh;
        uint* proW   = (uint*)(ws + off); off += sz_proW;
        uint* hA     = (uint*)(ws + off); off += sz_h;
        uint* hB     = (uint*)(ws + off); off += sz_h;
        float* hparts= (float*)(ws + off); off += sz_hp;
        float* ropar = (float*)(ws + off); off += sz_rp;
        float* done  = (float*)(ws + off); off += sz_done;
        uint* px     = (uint*)(ws + off);   // mode2: 65 steps; mode1: 1 slot

        split_pack2_k<<<dim3(1024), dim3(256), 0, stream>>>(eWih, pWih,  Hsz*Isz);
        split_pack2_k<<<dim3(2048), dim3(256), 0, stream>>>(eWhh, pWhh,  Hsz*Hsz);
        split_pack2_k<<<dim3(2048), dim3(256), 0, stream>>>(dWhh, pdWhh, Hsz*Hsz);
        split_pack2_k<<<dim3(1024), dim3(256), 0, stream>>>(roW,  proW,  Isz*Hsz);
        if (mode == 2)
            split_pack2_k<<<dim3(2048), dim3(256), 0, stream>>>(x, px, Tenc*BI);

        hipMemsetAsync(hA,   0, sz_h,    stream);
        hipMemsetAsync(done, 0, sz_done, stream);

        uint* h[2] = { hA, hB };
        int cur = 0;
        // ---- encoder: K = 512 + 2048, KS=4 -> 512 blocks (2/CU) ----
        for (int t = 0; t < Tenc; ++t) {
            const uint* xs;
            if (mode == 2) xs = px + (size_t)t * BI;
            else {
                split_pack2_k<<<dim3(512), dim3(256), 0, stream>>>(
                    x + (size_t)t * BI, px, BI);
                xs = px;
            }
            gemm_pk4<<<dim3(512), dim3(256), 0, stream>>>(
                xs, Isz, pWih, h[cur], Hsz, pWhh,
                hparts, Bsz, Hsz, 8, 16, 4);
            combine_h4<<<dim3(1024), dim3(256), 0, stream>>>(
                hparts, ebih, ebhh, h[cur ^ 1]);
            cur ^= 1;
        }
        // ---- decoder prologue: h_1 = tanh(bias + h_enc @ Whh^T) ----
        gemm_pk4<<<dim3(512), dim3(256), 0, stream>>>(
            nullptr, 0, nullptr, h[cur], Hsz, pdWhh,
            hparts, Bsz, Hsz, 8, 16, 4);
        combine_h4<<<dim3(1024), dim3(256), 0, stream>>>(
            hparts, dbih, dbhh, h[cur ^ 1]);
        cur ^= 1;
        // ---- decoder: 64 steps x 2 fused launches ----
        // dec_work: h-GEMM (512, wave1) || ro KS=8 (256 short backfill)
        // dec_fin : combine || softmax(8 partials)
        for (int t = 0; t < Tdec; ++t) {
            const int doH = (t + 1 < Tdec) ? 1 : 0;
            dec_work<<<dim3(768), dim3(256), 0, stream>>>(
                h[cur], pdWhh, proW, hparts, ropar, doH);
            dec_fin<<<dim3(2048), dim3(256), 0, stream>>>(
                hparts, dbih, dbhh, h[cur ^ 1],
                ropar, rob, done, out + (size_t)t * BI, doH);
            cur ^= 1;
        }
        return;
    }

    // ================= fallback path (tiny ws) =================
    {
        const size_t sz_lg = (size_t)BI * 4;
        size_t off = 0;
        uint*  hA     = (uint*)(ws + off); off += sz_h;
        uint*  hB     = (uint*)(ws + off); off += sz_h;
        float* logits = (float*)(ws + off); off += sz_lg;
        float* done   = (float*)(ws + off);

        hipMemsetAsync(hA, 0, sz_h, stream);
        hipMemsetAsync(done, 0, sz_done, stream);

        uint* h[2] = { hA, hB };
        const dim3 blk(256);
        const dim3 grid_h(Hsz / 128, Bsz / 64);
        const dim3 grid_ro(Isz / 64, Bsz / 64);

        int cur = 0;
        for (int t = 0; t < Tenc; ++t) {
            gemm_sp<64, 128, 2, 2, 2, 4, true, true><<<grid_h, blk, 0, stream>>>(
                x + (size_t)t * BI, Isz, eWih,
                h[cur], Hsz, eWhh, 1,
                ebih, ebhh, h[cur ^ 1], Bsz, Hsz);
            cur ^= 1;
        }
        for (int t = 0; t < Tdec; ++t) {
            gemm_sp<64, 128, 2, 2, 2, 4, true, true><<<grid_h, blk, 0, stream>>>(
                nullptr, 0, nullptr, h[cur], Hsz, dWhh, 1,
                dbih, dbhh, h[cur ^ 1], Bsz, Hsz);
            cur ^= 1;
            gemm_sp<64, 64, 2, 2, 2, 2, false, false><<<grid_ro, blk, 0, stream>>>(
                nullptr, 0, nullptr, h[cur], Hsz, roW, 1,
                rob, nullptr, logits, Bsz, Isz);
            logsoftmax_done1<<<dim3(Bsz), dim3(256), 0, stream>>>(
                logits, rob, done, out + (size_t)t * BI);
        }
    }
}